// Round 7
// baseline (129.573 us; speedup 1.0000x reference)
//
#include <hip/hip_runtime.h>
#include <hip/hip_bf16.h>

// Problem constants (fixed by the reference setup)
#define H_DIM  128
#define NGRAPH 8192
#define NTOTAL 409600
#define TAILW  512     // extra waves for the (single) large last graph

typedef __attribute__((ext_vector_type(8))) short    s16x8;   // 8 bf16
typedef __attribute__((ext_vector_type(4))) float    f32x4;   // MFMA accumulator
typedef __attribute__((ext_vector_type(4))) unsigned u32x4;

__device__ __forceinline__ unsigned short f2bf(float f) {
    unsigned int u = __float_as_uint(f);
    unsigned int r = u + 0x7fffu + ((u >> 16) & 1u);   // RNE
    return (unsigned short)(r >> 16);
}

// ---------------- K0: W2 f32 -> bf16 (row-major [h][k]) ----------------
__global__ void k0_w2(const float* __restrict__ W2w, unsigned short* __restrict__ w2bf) {
    int i = blockIdx.x * 256 + threadIdx.x;   // grid covers exactly 128*128
    w2bf[i] = f2bf(W2w[i]);
}

// ---------------- K1: a_g = v_n @ W1^T + (W1_b + W2_b); zero s_g -------
__global__ __launch_bounds__(128) void k1_ag(
    const float* __restrict__ node_emb,
    const int*   __restrict__ last_idx,
    const float* __restrict__ W1w,
    const float* __restrict__ W1b,
    const float* __restrict__ W2b,
    float* __restrict__ a_g,
    float* __restrict__ s_g)
{
    __shared__ float vn[4][H_DIM];
    const int tid = threadIdx.x;
    const int g0  = blockIdx.x * 4;
    #pragma unroll
    for (int g = 0; g < 4; g++) {
        int li = last_idx[g0 + g];
        vn[g][tid] = node_emb[(size_t)li * H_DIM + tid];
        s_g[(size_t)(g0 + g) * H_DIM + tid] = 0.f;   // needed for tail-graph atomics
    }
    __syncthreads();
    float b = W1b[tid] + W2b[tid];
    float a0 = b, a1 = b, a2 = b, a3 = b;
    const float* wrow = W1w + (size_t)tid * H_DIM;
    #pragma unroll 8
    for (int k = 0; k < H_DIM; k += 4) {
        float4 w = *reinterpret_cast<const float4*>(wrow + k);
        a0 += w.x * vn[0][k] + w.y * vn[0][k+1] + w.z * vn[0][k+2] + w.w * vn[0][k+3];
        a1 += w.x * vn[1][k] + w.y * vn[1][k+1] + w.z * vn[1][k+2] + w.w * vn[1][k+3];
        a2 += w.x * vn[2][k] + w.y * vn[2][k+1] + w.z * vn[2][k+2] + w.w * vn[2][k+3];
        a3 += w.x * vn[3][k] + w.y * vn[3][k+1] + w.z * vn[3][k+2] + w.w * vn[3][k+3];
    }
    a_g[(size_t)(g0 + 0) * H_DIM + tid] = a0;
    a_g[(size_t)(g0 + 1) * H_DIM + tid] = a1;
    a_g[(size_t)(g0 + 2) * H_DIM + tid] = a2;
    a_g[(size_t)(g0 + 3) * H_DIM + tid] = a3;
}

// ---------------- K2: one WAVE per graph (no atomics, no run-loop) -----
// Wave items: [0, NGRAPH-1)   -> whole graph item (10..90 nodes, 1..6 tiles),
//             s_g row computed in registers, written with a plain store.
// [NGRAPH-1, NGRAPH-1+TAILW)  -> one 16-node tile of the big last graph,
//             accumulated into s_g[NGRAPH-1] with atomicAdd (zeroed by k1).
__global__ __launch_bounds__(256, 4) void k2_fused(
    const float* __restrict__ node_emb,
    const float* __restrict__ num_count,
    const int*   __restrict__ last_idx,
    const float* __restrict__ a_g,
    const unsigned short* __restrict__ w2bf,
    const float* __restrict__ q_w,
    const float* __restrict__ q_b,
    float* __restrict__ s_g)
{
    __shared__ __align__(16) char w2s[H_DIM * 256];   // 32 KB, swizzled

    const int tid = threadIdx.x;
    // --- stage W2 bf16 -> LDS (once per block), XOR swizzled ---
    {
        const uint4* wsrc = reinterpret_cast<const uint4*>(w2bf);
        #pragma unroll
        for (int i = 0; i < 8; i++) {
            int c = i * 256 + tid;
            uint4 v = wsrc[c];
            int byte = c << 4;
            int row  = byte >> 8;
            *reinterpret_cast<uint4*>(w2s + (byte ^ ((row & 7) << 4))) = v;
        }
    }

    const int lane = tid & 63;
    const int l16 = lane & 15, lq = lane >> 4;
    const int item = __builtin_amdgcn_readfirstlane(blockIdx.x * 4 + (tid >> 6));

    // --- work descriptor for this wave ---
    int g = 0, nstart = 0, nend = -1;
    bool tail = false, valid = true;
    if (item < NGRAPH - 1) {
        g      = item;
        nstart = item ? (last_idx[item - 1] + 1) : 0;
        nend   = last_idx[item];
    } else if (item < NGRAPH - 1 + TAILW) {
        g    = NGRAPH - 1;
        tail = true;
        int base = last_idx[NGRAPH - 2] + 1;
        int t0   = item - (NGRAPH - 1);
        nstart   = base + t0 * 16;
        int ge   = last_idx[NGRAPH - 1];
        if (nstart > ge) valid = false;
        else nend = min(ge, nstart + 15);
    } else {
        valid = false;
    }

    // identity B-fragments for the transpose MFMAs (loop-invariant)
    s16x8 ib[2];
    #pragma unroll
    for (int b = 0; b < 2; b++) {
        int kk = l16 + 16 * b;
        #pragma unroll
        for (int e = 0; e < 8; e++)
            ib[b][e] = (kk == lq * 8 + e) ? (short)0x3F80 : (short)0;
    }

    __syncthreads();   // w2s ready (only barrier)
    if (!valid) return;

    const float qb0 = q_b[0];
    const float* agrow = a_g + (size_t)g * H_DIM;

    float sgacc[4][2] = {{0.f, 0.f}, {0.f, 0.f}, {0.f, 0.f}, {0.f, 0.f}};

    for (int nb = nstart; nb <= nend; nb += 16) {
        const int vcnt = nend - nb + 1;               // valid rows this tile (>=1)
        const int idx  = min(nb + l16, nend);         // clamped node index

        // --- load node row (f32) + num_count ---
        const float* nrow = node_emb + (size_t)idx * H_DIM + lq * 8;
        float4 f[8];
        #pragma unroll
        for (int ks = 0; ks < 4; ks++) {
            f[2 * ks]     = *reinterpret_cast<const float4*>(nrow + ks * 32);
            f[2 * ks + 1] = *reinterpret_cast<const float4*>(nrow + ks * 32 + 4);
        }
        const float ncl = num_count[idx];

        // --- cvt f32 -> bf16 A/B fragments (row l16, k = lq*8 + ks*32 ..) ---
        s16x8 af[4];
        #pragma unroll
        for (int ks = 0; ks < 4; ks++) {
            unsigned p0, p1, p2, p3;
            asm("v_cvt_pk_bf16_f32 %0, %1, %2" : "=v"(p0) : "v"(f[2*ks].x),   "v"(f[2*ks].y));
            asm("v_cvt_pk_bf16_f32 %0, %1, %2" : "=v"(p1) : "v"(f[2*ks].z),   "v"(f[2*ks].w));
            asm("v_cvt_pk_bf16_f32 %0, %1, %2" : "=v"(p2) : "v"(f[2*ks+1].x), "v"(f[2*ks+1].y));
            asm("v_cvt_pk_bf16_f32 %0, %1, %2" : "=v"(p3) : "v"(f[2*ks+1].z), "v"(f[2*ks+1].w));
            union { u32x4 u; s16x8 s; } cv;
            cv.u = u32x4{p0, p1, p2, p3};
            af[ks] = cv.s;
        }

        // --- identity-MFMA transpose: accT[ks][b][rr] = node[lq*4+rr][ks*32+b*16+l16]
        f32x4 accT[4][2];
        #pragma unroll
        for (int ks = 0; ks < 4; ks++)
            #pragma unroll
            for (int b = 0; b < 2; b++)
                accT[ks][b] = __builtin_amdgcn_mfma_f32_16x16x32_bf16(
                                  af[ks], ib[b], f32x4{0.f, 0.f, 0.f, 0.f}, 0, 0, 0);

        // --- swapped z-MFMA: lane holds z[l16][h], h = nt*16 + lq*4 + rr ---
        f32x4 acc[8];
        #pragma unroll
        for (int nt = 0; nt < 8; nt++) acc[nt] = f32x4{0.f, 0.f, 0.f, 0.f};
        #pragma unroll
        for (int ks = 0; ks < 4; ks++) {
            #pragma unroll
            for (int nt = 0; nt < 8; nt++) {
                int row  = nt * 16 + l16;
                int byte = (row << 8) | ((lq * 8 + ks * 32) << 1);
                byte ^= (row & 7) << 4;
                s16x8 wfr = *reinterpret_cast<const s16x8*>(w2s + byte);
                acc[nt] = __builtin_amdgcn_mfma_f32_16x16x32_bf16(wfr, af[ks], acc[nt], 0, 0, 0);
            }
        }

        // --- alpha: sum_h sigmoid(z + a_g[h]) * q_w[h]  (a_g wave-uniform) ---
        float pp0 = 0.f, pp1 = 0.f, pp2 = 0.f, pp3 = 0.f;
        #pragma unroll
        for (int nt = 0; nt < 8; nt++) {
            float4 q4 = *reinterpret_cast<const float4*>(q_w + nt * 16 + lq * 4);
            float4 a4 = *reinterpret_cast<const float4*>(agrow + nt * 16 + lq * 4);
            float z0 = acc[nt][0] + a4.x;
            float z1 = acc[nt][1] + a4.y;
            float z2 = acc[nt][2] + a4.z;
            float z3 = acc[nt][3] + a4.w;
            pp0 += q4.x * __builtin_amdgcn_rcpf(1.f + __expf(-z0));
            pp1 += q4.y * __builtin_amdgcn_rcpf(1.f + __expf(-z1));
            pp2 += q4.z * __builtin_amdgcn_rcpf(1.f + __expf(-z2));
            pp3 += q4.w * __builtin_amdgcn_rcpf(1.f + __expf(-z3));
        }
        float p = (pp0 + pp1) + (pp2 + pp3);
        p += __shfl_xor(p, 16, 64);
        p += __shfl_xor(p, 32, 64);
        const float coefl = ncl * (p + qb0);          // coef of node row l16

        // --- distribute coef to the rows this lane owns in accT ---
        float cm[4];
        #pragma unroll
        for (int rr = 0; rr < 4; rr++) {
            int r = lq * 4 + rr;
            float c = __shfl(coefl, r, 64);
            cm[rr] = (r < vcnt) ? c : 0.f;
        }

        // --- per-lane partial of s_g[g][h] (no shuffles, no atomics) ---
        #pragma unroll
        for (int ks = 0; ks < 4; ks++)
            #pragma unroll
            for (int b = 0; b < 2; b++)
                sgacc[ks][b] += cm[0] * accT[ks][b][0] + cm[1] * accT[ks][b][1]
                              + cm[2] * accT[ks][b][2] + cm[3] * accT[ks][b][3];
    }

    // --- fold lq quadrants and write the graph's s_g row ---
    #pragma unroll
    for (int ks = 0; ks < 4; ks++) {
        #pragma unroll
        for (int b = 0; b < 2; b++) {
            float s = sgacc[ks][b];
            s += __shfl_xor(s, 16, 64);
            s += __shfl_xor(s, 32, 64);
            if (lq == 0) {
                float* dst = s_g + (size_t)g * H_DIM + ks * 32 + b * 16 + l16;
                if (tail) atomicAdd(dst, s);
                else      *dst = s;
            }
        }
    }
}

// ---------------- K3: s_h = [v_n | s_g] @ W3^T + W3_b ------------------
__global__ __launch_bounds__(128) void k3_out(
    const float* __restrict__ node_emb,
    const int*   __restrict__ last_idx,
    const float* __restrict__ s_g,
    const float* __restrict__ W3w,
    const float* __restrict__ W3b,
    float* __restrict__ out)
{
    __shared__ float cat[8][2 * H_DIM];
    const int tid = threadIdx.x;
    const int g0  = blockIdx.x * 8;
    #pragma unroll
    for (int g = 0; g < 8; g++) {
        cat[g][tid]         = node_emb[(size_t)last_idx[g0 + g] * H_DIM + tid];
        cat[g][H_DIM + tid] = s_g[(size_t)(g0 + g) * H_DIM + tid];
    }
    __syncthreads();
    float acc[8];
    float b = W3b[tid];
    #pragma unroll
    for (int g = 0; g < 8; g++) acc[g] = b;
    const float* wrow = W3w + (size_t)tid * (2 * H_DIM);
    for (int k = 0; k < 2 * H_DIM; k += 4) {
        float4 w = *reinterpret_cast<const float4*>(wrow + k);
        #pragma unroll
        for (int g = 0; g < 8; g++)
            acc[g] += w.x * cat[g][k] + w.y * cat[g][k+1]
                    + w.z * cat[g][k+2] + w.w * cat[g][k+3];
    }
    #pragma unroll
    for (int g = 0; g < 8; g++)
        out[(size_t)(g0 + g) * H_DIM + tid] = acc[g];
}

extern "C" void kernel_launch(void* const* d_in, const int* in_sizes, int n_in,
                              void* d_out, int out_size, void* d_ws, size_t ws_size,
                              hipStream_t stream) {
    const float* node_emb  = (const float*)d_in[0];
    const float* num_count = (const float*)d_in[1];
    // d_in[2] sections, d_in[3] segment_ids: unused (graph ownership via last_idx)
    const int*   last_idx  = (const int*)d_in[4];
    // d_in[5..8] unused
    const float* W1w = (const float*)d_in[9];
    const float* W1b = (const float*)d_in[10];
    const float* W2w = (const float*)d_in[11];
    const float* W2b = (const float*)d_in[12];
    const float* qw  = (const float*)d_in[13];
    const float* qb  = (const float*)d_in[14];
    const float* W3w = (const float*)d_in[15];
    const float* W3b = (const float*)d_in[16];
    float* out = (float*)d_out;

    char* ws = (char*)d_ws;
    float* a_g = (float*)(ws);                          // 4 MB
    float* s_g = (float*)(ws + (4u << 20));             // 4 MB
    unsigned short* w2bf = (unsigned short*)(ws + (8u << 20));   // 32 KB

    const int items  = (NGRAPH - 1) + TAILW;            // 8703 wave work items
    const int blocks = (items + 3) / 4;                 // 4 waves per block

    k0_w2   <<<64,         256, 0, stream>>>(W2w, w2bf);
    k1_ag   <<<NGRAPH / 4, 128, 0, stream>>>(node_emb, last_idx, W1w, W1b, W2b, a_g, s_g);
    k2_fused<<<blocks,     256, 0, stream>>>(node_emb, num_count, last_idx, a_g,
                                             w2bf, qw, qb, s_g);
    k3_out  <<<NGRAPH / 8, 128, 0, stream>>>(node_emb, last_idx, s_g, W3w, W3b, out);
}